// Round 1
// baseline (22526.996 us; speedup 1.0000x reference)
//
#include <hip/hip_runtime.h>

#define B_   64
#define T_   512
#define KIN  512
#define NH   512
#define KEFF 3072   // 6 segments x 512
#define NBLK 64
#define NTHR 256

typedef __attribute__((ext_vector_type(8))) short short8;
typedef __attribute__((ext_vector_type(4))) float f32x4;
typedef __attribute__((ext_vector_type(4))) float float4v;

// bf16 round-to-nearest-even via bit ops (no header dependency)
__device__ __forceinline__ unsigned short f2b(float f) {
    union { float f; unsigned int u; } v; v.f = f;
    unsigned int u = v.u;
    unsigned int r = (u + 0x7FFFu + ((u >> 16) & 1u)) >> 16;
    return (unsigned short)r;
}
__device__ __forceinline__ float b2f(unsigned short h) {
    union { float f; unsigned int u; } v; v.u = ((unsigned int)h) << 16;
    return v.f;
}

// ---------------------------------------------------------------------------
// Prepack: build B' [n][keff] bf16, n-major, k-contiguous, so MFMA B-frags are
// direct 16B loads. Segments (must match A-side [Ahi|Alo|Ahi|Xhi|Xlo|Xhi]):
//   seg0: Whi(H)  seg1: Whi(H)  seg2: Wlo(H)  seg3: Whi(X)  seg4: Whi(X)  seg5: Wlo(X)
// n in [0,512): z-gate (Whz/Wxz); [512,1024): r-gate; [1024,1536): h-gate (Whh/Wxh)
// ---------------------------------------------------------------------------
__global__ void prepack(const float* __restrict__ Wxz, const float* __restrict__ Whz,
                        const float* __restrict__ Wxr, const float* __restrict__ Whr,
                        const float* __restrict__ Wxh, const float* __restrict__ Whh,
                        unsigned short* __restrict__ Bzr, unsigned short* __restrict__ Bh) {
    int keff = blockIdx.x * 256 + threadIdx.x;  // 0..3071
    int n    = blockIdx.y;                      // 0..1535
    int seg  = keff >> 9;
    int k    = keff & 511;
    const float* src;
    int c;
    if (n < 512)       { c = n;        src = (seg < 3) ? Whz : Wxz; }
    else if (n < 1024) { c = n - 512;  src = (seg < 3) ? Whr : Wxr; }
    else               { c = n - 1024; src = (seg < 3) ? Whh : Wxh; }
    float w = src[k * NH + c];
    unsigned short hi = f2b(w);
    unsigned short o  = (seg == 2 || seg == 5) ? f2b(w - b2f(hi)) : hi;
    if (n < 1024) Bzr[(size_t)n * KEFF + keff] = o;
    else          Bh[(size_t)(n - 1024) * KEFF + keff] = o;
}

// ---------------------------------------------------------------------------
// Grid barrier: monotonic counter, agent-scope. All 64 blocks are co-resident
// (64 blocks <= 256 CUs), so spin is safe. Counter zeroed by memset each launch.
// ---------------------------------------------------------------------------
__device__ __forceinline__ void gridbar(unsigned int* cnt, unsigned int target) {
    __syncthreads();
    if (threadIdx.x == 0) {
        __threadfence();  // agent-scope release of this block's stores
        __hip_atomic_fetch_add(cnt, 1u, __ATOMIC_RELEASE, __HIP_MEMORY_SCOPE_AGENT);
        while (__hip_atomic_load(cnt, __ATOMIC_ACQUIRE, __HIP_MEMORY_SCOPE_AGENT) < target) {
            __builtin_amdgcn_s_sleep(2);
        }
    }
    __syncthreads();
}

// ---------------------------------------------------------------------------
// Persistent GRU kernel. 64 blocks x 256 threads (4 waves).
// Phase 1: z|r preacts. Block b owns zr-ntile b (16 cols); wave w owns mtile w.
//          GEMM K_eff=3072: [Hhi|Hlo|Hhi|Xhi|Xlo|Xhi] x Bzr'. Sigmoid; store Z
//          (fp32) or RH=R*H split to bf16 hi/lo.
// Phase 2: h~ = tanh(Xh + RH@Whh + bh); H_new = Z*H + (1-Z)*h~. 128 tile-tasks,
//          2 per block, K split across wave pairs (RH-half / X-half), LDS combine.
// MFMA 16x16x32 bf16 layouts: A/B: idx16=lane&15, k=(lane>>4)*8+i (k-contiguous
// 16B per lane); C/D: col=lane&15, row=(lane>>4)*4+reg.
// ---------------------------------------------------------------------------
__global__ void __launch_bounds__(NTHR) gru_seq(
    const float* __restrict__ X, const float* __restrict__ bz,
    const float* __restrict__ br, const float* __restrict__ bh,
    float* __restrict__ out,
    float* __restrict__ Hf, float* __restrict__ Zbuf,
    unsigned short* __restrict__ Hhi, unsigned short* __restrict__ Hlo,
    unsigned short* __restrict__ RHhi, unsigned short* __restrict__ RHlo,
    const unsigned short* __restrict__ Bzr, const unsigned short* __restrict__ Bh,
    unsigned int* cnt) {
    const int blk  = blockIdx.x;
    const int tid  = threadIdx.x;
    const int wv   = tid >> 6;
    const int lane = tid & 63;
    const int fm   = lane & 15;      // A-row / B-col / C-col index within 16
    const int fkc  = lane >> 4;      // k-chunk 0..3
    const int fk   = fkc * 8;

    __shared__ float comb[2][256];

    unsigned int ep = 0;

    for (int t = 0; t < T_; ++t) {
        // ------------------------- phase 1: Z and R -------------------------
        {
            const int nt = blk;            // zr ntile 0..63 (z: 0..31, r: 32..63)
            const int mt = wv;             // mtile 0..3
            const int m  = mt * 16 + fm;   // batch row
            const int nrow = nt * 16 + fm; // B' row
            const unsigned short* Bp = Bzr + (size_t)nrow * KEFF;
            f32x4 acc = {0.f, 0.f, 0.f, 0.f};

            // H part: segs 0..2 ([Hhi|Hlo|Hhi] x [Whi;Whi;Wlo])
            const unsigned short* hh = Hhi + m * NH;
            const unsigned short* hl = Hlo + m * NH;
#pragma unroll 4
            for (int j = 0; j < 16; ++j) {
                int kp = j * 32 + fk;
                short8 ahi = *(const short8*)(hh + kp);
                short8 alo = *(const short8*)(hl + kp);
                short8 b0  = *(const short8*)(Bp + kp);
                short8 b1  = *(const short8*)(Bp + 512 + kp);
                short8 b2  = *(const short8*)(Bp + 1024 + kp);
                acc = __builtin_amdgcn_mfma_f32_16x16x32_bf16(ahi, b0, acc, 0, 0, 0);
                acc = __builtin_amdgcn_mfma_f32_16x16x32_bf16(alo, b1, acc, 0, 0, 0);
                acc = __builtin_amdgcn_mfma_f32_16x16x32_bf16(ahi, b2, acc, 0, 0, 0);
            }
            // X part: segs 3..5, split fp32 X in-register
            const float* xr = X + (size_t)m * (T_ * KIN) + (size_t)t * KIN;
#pragma unroll 4
            for (int j = 0; j < 16; ++j) {
                int kp = j * 32 + fk;
                float4v x0 = *(const float4v*)(xr + kp);
                float4v x1 = *(const float4v*)(xr + kp + 4);
                short8 ahi, alo;
#pragma unroll
                for (int i = 0; i < 4; ++i) {
                    unsigned short h0 = f2b(x0[i]);
                    ahi[i] = (short)h0; alo[i] = (short)f2b(x0[i] - b2f(h0));
                    unsigned short h1 = f2b(x1[i]);
                    ahi[4 + i] = (short)h1; alo[4 + i] = (short)f2b(x1[i] - b2f(h1));
                }
                short8 b3 = *(const short8*)(Bp + 1536 + kp);
                short8 b4 = *(const short8*)(Bp + 2048 + kp);
                short8 b5 = *(const short8*)(Bp + 2560 + kp);
                acc = __builtin_amdgcn_mfma_f32_16x16x32_bf16(ahi, b3, acc, 0, 0, 0);
                acc = __builtin_amdgcn_mfma_f32_16x16x32_bf16(alo, b4, acc, 0, 0, 0);
                acc = __builtin_amdgcn_mfma_f32_16x16x32_bf16(ahi, b5, acc, 0, 0, 0);
            }
            // epilogue: C frag -> sigmoid -> Z store or RH split-store
            const int c = nt * 16 + fm;  // zr col 0..1023
#pragma unroll
            for (int jj = 0; jj < 4; ++jj) {
                int mrow = mt * 16 + fkc * 4 + jj;
                if (c < 512) {
                    float p = acc[jj] + bz[c];
                    float g = 1.f / (1.f + __expf(-p));
                    Zbuf[mrow * NH + c] = g;
                } else {
                    int cr = c - 512;
                    float p = acc[jj] + br[cr];
                    float g = 1.f / (1.f + __expf(-p));
                    float rh = g * Hf[mrow * NH + cr];
                    unsigned short hi = f2b(rh);
                    RHhi[mrow * NH + cr] = hi;
                    RHlo[mrow * NH + cr] = f2b(rh - b2f(hi));
                }
            }
        }
        gridbar(cnt, (unsigned int)(NBLK * (++ep)));

        // ------------------------- phase 2: h~ and H update ------------------
        {
            const int task  = blk * 2 + (wv >> 1);  // 0..127
            const int mt    = task & 3;
            const int nt    = task >> 2;            // 0..31
            const int khalf = wv & 1;               // 0: RH segs 0..2, 1: X segs 3..5
            const int m     = mt * 16 + fm;
            const int nrow  = nt * 16 + fm;
            const unsigned short* Bp = Bh + (size_t)nrow * KEFF;
            f32x4 acc = {0.f, 0.f, 0.f, 0.f};

            if (khalf == 0) {
                const unsigned short* rh_ = RHhi + m * NH;
                const unsigned short* rl_ = RHlo + m * NH;
#pragma unroll 4
                for (int j = 0; j < 16; ++j) {
                    int kp = j * 32 + fk;
                    short8 ahi = *(const short8*)(rh_ + kp);
                    short8 alo = *(const short8*)(rl_ + kp);
                    short8 b0  = *(const short8*)(Bp + kp);
                    short8 b1  = *(const short8*)(Bp + 512 + kp);
                    short8 b2  = *(const short8*)(Bp + 1024 + kp);
                    acc = __builtin_amdgcn_mfma_f32_16x16x32_bf16(ahi, b0, acc, 0, 0, 0);
                    acc = __builtin_amdgcn_mfma_f32_16x16x32_bf16(alo, b1, acc, 0, 0, 0);
                    acc = __builtin_amdgcn_mfma_f32_16x16x32_bf16(ahi, b2, acc, 0, 0, 0);
                }
            } else {
                const float* xr = X + (size_t)m * (T_ * KIN) + (size_t)t * KIN;
#pragma unroll 4
                for (int j = 0; j < 16; ++j) {
                    int kp = j * 32 + fk;
                    float4v x0 = *(const float4v*)(xr + kp);
                    float4v x1 = *(const float4v*)(xr + kp + 4);
                    short8 ahi, alo;
#pragma unroll
                    for (int i = 0; i < 4; ++i) {
                        unsigned short h0 = f2b(x0[i]);
                        ahi[i] = (short)h0; alo[i] = (short)f2b(x0[i] - b2f(h0));
                        unsigned short h1 = f2b(x1[i]);
                        ahi[4 + i] = (short)h1; alo[4 + i] = (short)f2b(x1[i] - b2f(h1));
                    }
                    short8 b3 = *(const short8*)(Bp + 1536 + kp);
                    short8 b4 = *(const short8*)(Bp + 2048 + kp);
                    short8 b5 = *(const short8*)(Bp + 2560 + kp);
                    acc = __builtin_amdgcn_mfma_f32_16x16x32_bf16(ahi, b3, acc, 0, 0, 0);
                    acc = __builtin_amdgcn_mfma_f32_16x16x32_bf16(alo, b4, acc, 0, 0, 0);
                    acc = __builtin_amdgcn_mfma_f32_16x16x32_bf16(ahi, b5, acc, 0, 0, 0);
                }
            }

            const int slot = wv >> 1;
            if (khalf == 1) {
#pragma unroll
                for (int jj = 0; jj < 4; ++jj)
                    comb[slot][(fkc * 4 + jj) * 16 + fm] = acc[jj];
            }
            __syncthreads();
            if (khalf == 0) {
#pragma unroll
                for (int jj = 0; jj < 4; ++jj) {
                    int mrow = mt * 16 + fkc * 4 + jj;
                    int c    = nt * 16 + fm;
                    float pre = acc[jj] + comb[slot][(fkc * 4 + jj) * 16 + fm] + bh[c];
                    float e  = __expf(-2.f * pre);
                    float ht = 2.f / (1.f + e) - 1.f;       // tanh
                    float z  = Zbuf[mrow * NH + c];
                    float h  = Hf[mrow * NH + c];
                    float hn = z * h + (1.f - z) * ht;
                    out[(size_t)mrow * (T_ * NH) + (size_t)t * NH + c] = hn;
                    if (t == T_ - 1)
                        out[(size_t)B_ * T_ * NH + mrow * NH + c] = hn;
                    Hf[mrow * NH + c] = hn;
                    unsigned short hi = f2b(hn);
                    Hhi[mrow * NH + c] = hi;
                    Hlo[mrow * NH + c] = f2b(hn - b2f(hi));
                }
            }
        }
        gridbar(cnt, (unsigned int)(NBLK * (++ep)));
    }
}

extern "C" void kernel_launch(void* const* d_in, const int* in_sizes, int n_in,
                              void* d_out, int out_size, void* d_ws, size_t ws_size,
                              hipStream_t stream) {
    (void)in_sizes; (void)n_in; (void)out_size; (void)ws_size;
    const float* X   = (const float*)d_in[0];
    const float* Wxz = (const float*)d_in[1];
    const float* Whz = (const float*)d_in[2];
    const float* bz  = (const float*)d_in[3];
    const float* Wxr = (const float*)d_in[4];
    const float* Whr = (const float*)d_in[5];
    const float* br  = (const float*)d_in[6];
    const float* Wxh = (const float*)d_in[7];
    const float* Whh = (const float*)d_in[8];
    const float* bh  = (const float*)d_in[9];
    float* out = (float*)d_out;

    char* ws = (char*)d_ws;
    unsigned int* cnt = (unsigned int*)ws;                       // 256 B reserved
    float* Hf   = (float*)(ws + 256);                            // 128 KB
    float* Zbuf = (float*)(ws + 256 + 131072);                   // 128 KB
    unsigned short* Hhi  = (unsigned short*)(ws + 256 + 262144); // 64 KB each
    unsigned short* Hlo  = Hhi  + 64 * 512;
    unsigned short* RHhi = Hlo  + 64 * 512;
    unsigned short* RHlo = RHhi + 64 * 512;
    unsigned short* Bzr  = (unsigned short*)(ws + (1 << 20));    // 6 MB
    unsigned short* Bh   = Bzr + (size_t)1024 * KEFF;            // 3 MB

    // zero barrier counter + H state (H0 = 0) every call (graph-replay safe)
    hipMemsetAsync(d_ws, 0, 1 << 20, stream);
    prepack<<<dim3(12, 1536), 256, 0, stream>>>(Wxz, Whz, Wxr, Whr, Wxh, Whh, Bzr, Bh);
    gru_seq<<<NBLK, NTHR, 0, stream>>>(X, bz, br, bh, out, Hf, Zbuf,
                                       Hhi, Hlo, RHhi, RHlo, Bzr, Bh, cnt);
}